// Round 1
// baseline (1416.817 us; speedup 1.0000x reference)
//
#include <hip/hip_runtime.h>
#include <hip/hip_bf16.h>
#include <math.h>

// Problem constants
#define Bb   256
#define Nn   400
#define FIN  400
#define Hh   64
#define NNZ  16000
#define Mrows (Bb*Nn)          // 102400
#define BH_COUNT 16384.0f      // B*H for BN3 stats

// ---------------------------------------------------------------------------
// init: zero CSR counts + BN stats accumulators
// ---------------------------------------------------------------------------
__global__ void initk(int* __restrict__ counts, float* __restrict__ stats) {
    int t = blockIdx.x * blockDim.x + threadIdx.x;
    if (t < Nn) counts[t] = 0;
    if (t < 1600) stats[t] = 0.f;   // ssum1, ssq1, ssum2, ssq2 (4 x 400)
}

__global__ void countk(const int* __restrict__ rows, int* __restrict__ counts) {
    int i = blockIdx.x * blockDim.x + threadIdx.x;
    if (i < NNZ) atomicAdd(&counts[rows[i]], 1);
}

// single-block Hillis-Steele scan over 400 (padded 512)
__global__ void scank(const int* __restrict__ counts, int* __restrict__ row_ptr,
                      int* __restrict__ cursor) {
    __shared__ int s[512];
    int t = threadIdx.x;
    int c = (t < Nn) ? counts[t] : 0;
    s[t] = c;
    __syncthreads();
    for (int off = 1; off < 512; off <<= 1) {
        int v = (t >= off) ? s[t - off] : 0;
        __syncthreads();
        s[t] += v;
        __syncthreads();
    }
    if (t < Nn) { int excl = s[t] - c; row_ptr[t] = excl; cursor[t] = excl; }
    if (t == Nn - 1) row_ptr[Nn] = s[Nn - 1];
}

__global__ void scatterk(const int* __restrict__ rows, const int* __restrict__ cols,
                         const float* __restrict__ vals, int* __restrict__ cursor,
                         int* __restrict__ ci, float* __restrict__ cv) {
    int i = blockIdx.x * blockDim.x + threadIdx.x;
    if (i < NNZ) {
        int r = rows[i];
        int p = atomicAdd(&cursor[r], 1);
        ci[p] = cols[i];
        cv[p] = vals[i];
    }
}

// ---------------------------------------------------------------------------
// GEMM: C[M,64] = A[M,KT] @ W[KT,64], optional fused BN affine on A-side:
//   C = inv[r] * (A@W - mean[r]*colsum(W)),  r = row % 400
// Tile 64x64, 256 threads, 4x4 per thread, K-step 16.
// ---------------------------------------------------------------------------
template <int KT, bool AFFINE>
__global__ __launch_bounds__(256) void gemm64(
        const float* __restrict__ A, const float* __restrict__ W,
        float* __restrict__ C, const float* __restrict__ mean,
        const float* __restrict__ inv) {
    __shared__ float As[16][68];
    __shared__ float Bs[16][64];
    __shared__ float cs[64];
    const int t  = threadIdx.x;
    const int tx = t & 15, ty = t >> 4;
    const int m0 = blockIdx.x * 64;

    if (AFFINE) {
        if (t < 64) {
            float s = 0.f;
            for (int k = 0; k < KT; ++k) s += W[k * 64 + t];
            cs[t] = s;
        }
    }

    const int lr  = t >> 2;   // 0..63 A row
    const int lc4 = t & 3;    // float4 col (of 16)
    const int wk  = t >> 4;   // 0..15 W row
    const int wc4 = t & 15;   // float4 col (of 64)

    float acc[4][4];
#pragma unroll
    for (int i = 0; i < 4; ++i)
#pragma unroll
        for (int j = 0; j < 4; ++j) acc[i][j] = 0.f;

    for (int k0 = 0; k0 < KT; k0 += 16) {
        float4 av = *reinterpret_cast<const float4*>(
            &A[(size_t)(m0 + lr) * KT + k0 + lc4 * 4]);
        float4 wv = *reinterpret_cast<const float4*>(
            &W[(size_t)(k0 + wk) * 64 + wc4 * 4]);
        __syncthreads();
        As[lc4 * 4 + 0][lr] = av.x;
        As[lc4 * 4 + 1][lr] = av.y;
        As[lc4 * 4 + 2][lr] = av.z;
        As[lc4 * 4 + 3][lr] = av.w;
        *reinterpret_cast<float4*>(&Bs[wk][wc4 * 4]) = wv;
        __syncthreads();
#pragma unroll
        for (int k = 0; k < 16; ++k) {
            float4 a4 = *reinterpret_cast<const float4*>(&As[k][ty * 4]);
            float4 b4 = *reinterpret_cast<const float4*>(&Bs[k][tx * 4]);
            float a[4] = {a4.x, a4.y, a4.z, a4.w};
            float b[4] = {b4.x, b4.y, b4.z, b4.w};
#pragma unroll
            for (int i = 0; i < 4; ++i)
#pragma unroll
                for (int j = 0; j < 4; ++j) acc[i][j] += a[i] * b[j];
        }
    }

#pragma unroll
    for (int i = 0; i < 4; ++i) {
        int g = m0 + ty * 4 + i;
        float mm = 0.f, iv = 1.f;
        if (AFFINE) {
            int r = g % Nn;
            mm = mean[r];
            iv = inv[r];
        }
        float res[4];
#pragma unroll
        for (int j = 0; j < 4; ++j) {
            float u = acc[i][j];
            if (AFFINE) u = iv * (u - mm * cs[tx * 4 + j]);
            res[j] = u;
        }
        *reinterpret_cast<float4*>(&C[(size_t)g * 64 + tx * 4]) =
            make_float4(res[0], res[1], res[2], res[3]);
    }
}

// ---------------------------------------------------------------------------
// Sparse aggregation + bias + L2-normalize (+ relu + BN3 stat partials).
// One block per batch b; whole U[b] (400x64 f32 = 100 KB) staged in LDS.
// 512 threads = 8 waves; lane = feature o; each wave owns rows r = w, w+8, ...
// ---------------------------------------------------------------------------
template <bool RELU_STATS>
__global__ __launch_bounds__(512) void aggk(
        const float* __restrict__ U, const int* __restrict__ rp,
        const int* __restrict__ ci, const float* __restrict__ cv,
        const float* __restrict__ bias, float* __restrict__ Z,
        float* __restrict__ ssum, float* __restrict__ ssq) {
    __shared__ float Us[Nn * Hh];   // 102400 B
    const int b    = blockIdx.x;
    const int lane = threadIdx.x & 63;
    const int wave = threadIdx.x >> 6;

    const float* Ub = U + (size_t)b * Nn * Hh;
    for (int i = threadIdx.x; i < Nn * Hh / 4; i += 512)
        reinterpret_cast<float4*>(Us)[i] = reinterpret_cast<const float4*>(Ub)[i];
    __syncthreads();

    const float bv = bias[lane];
    for (int r = wave; r < Nn; r += 8) {
        float acc = bv;
        int s = rp[r], e = rp[r + 1];
        for (int j = s; j < e; ++j) {
            int   c = ci[j];
            float v = cv[j];
            acc += v * Us[c * Hh + lane];
        }
        float ss = acc * acc;
#pragma unroll
        for (int off = 32; off; off >>= 1) ss += __shfl_xor(ss, off);
        float nrm = sqrtf(ss);
        float z = acc / fmaxf(nrm, 1e-12f);
        if (RELU_STATS) z = fmaxf(z, 0.f);
        Z[((size_t)b * Nn + r) * Hh + lane] = z;
        if (RELU_STATS) {
            float s1 = z, s2 = z * z;
#pragma unroll
            for (int off = 32; off; off >>= 1) {
                s1 += __shfl_xor(s1, off);
                s2 += __shfl_xor(s2, off);
            }
            if (lane == 0) {
                atomicAdd(&ssum[r], s1);
                atomicAdd(&ssq[r], s2);
            }
        }
    }
}

__global__ void finalize_stats(const float* __restrict__ ssum,
                               const float* __restrict__ ssq,
                               float* __restrict__ mean, float* __restrict__ inv) {
    int r = threadIdx.x;
    if (r < Nn) {
        float m = ssum[r] * (1.0f / BH_COUNT);
        float v = ssq[r] * (1.0f / BH_COUNT) - m * m;
        mean[r] = m;
        inv[r]  = rsqrtf(v + 1e-5f);
    }
}

// ---------------------------------------------------------------------------
// out[b,h] = max_r affine(Z[b,r,h])   (affine = BN3, or identity for layer 3)
// Grid: 256 blocks (b), 256 threads (4 r-groups x 64 h)
// ---------------------------------------------------------------------------
template <bool AFF>
__global__ __launch_bounds__(256) void maxk(
        const float* __restrict__ Z, const float* __restrict__ mean,
        const float* __restrict__ inv, float* __restrict__ out) {
    __shared__ float red[4][64];
    const int b  = blockIdx.x;
    const int h  = threadIdx.x & 63;
    const int rg = threadIdx.x >> 6;
    float best = -3.4e38f;
    for (int r = rg; r < Nn; r += 4) {
        float v = Z[((size_t)b * Nn + r) * Hh + h];
        if (AFF) v = (v - mean[r]) * inv[r];
        best = fmaxf(best, v);
    }
    red[rg][h] = best;
    __syncthreads();
    if (threadIdx.x < 64) {
        float m = fmaxf(fmaxf(red[0][threadIdx.x], red[1][threadIdx.x]),
                        fmaxf(red[2][threadIdx.x], red[3][threadIdx.x]));
        out[b * Hh + threadIdx.x] = m;
    }
}

// ---------------------------------------------------------------------------
// FC head: h=[out1|out2|out3] (256x192) -> fc1+relu+bn2 -> fc2+relu+bn2 -> fc3
// Single block, 1024 threads: thread (r = t>>2, q = t&3) owns 16 cols.
// ---------------------------------------------------------------------------
__global__ __launch_bounds__(1024) void headk(
        const float* __restrict__ out1, const float* __restrict__ out2,
        const float* __restrict__ out3,
        const float* __restrict__ W1f, const float* __restrict__ b1f,
        const float* __restrict__ W2f, const float* __restrict__ b2f,
        const float* __restrict__ W3f, const float* __restrict__ b3f,
        float* __restrict__ ypred) {
    __shared__ float gA[256][64];     // 64 KB activations
    __shared__ float w1s[192 * 64];   // 48 KB
    __shared__ float w2s[64 * 64];    // 16 KB
    __shared__ float mS[64], iS[64];
    const int t = threadIdx.x;
    const int r = t >> 2, q = t & 3;

    for (int i = t; i < 192 * 64; i += 1024) w1s[i] = W1f[i];
    for (int i = t; i < 64 * 64; i += 1024) w2s[i] = W2f[i];
    __syncthreads();

    float acc[16];
#pragma unroll
    for (int j = 0; j < 16; ++j) acc[j] = b1f[q * 16 + j];
    for (int k = 0; k < 192; ++k) {
        float hv = (k < 64) ? out1[r * 64 + k]
                 : (k < 128) ? out2[r * 64 + (k - 64)]
                             : out3[r * 64 + (k - 128)];
#pragma unroll
        for (int j = 0; j < 16; ++j) acc[j] += hv * w1s[k * 64 + q * 16 + j];
    }
#pragma unroll
    for (int j = 0; j < 16; ++j) gA[r][q * 16 + j] = fmaxf(acc[j], 0.f);
    __syncthreads();

    if (t < 64) {
        float s = 0.f, s2 = 0.f;
        for (int rr = 0; rr < 256; ++rr) { float v = gA[rr][t]; s += v; s2 += v * v; }
        float m = s * (1.f / 256.f);
        float var = s2 * (1.f / 256.f) - m * m;
        mS[t] = m;
        iS[t] = rsqrtf(var + 1e-5f);
    }
    __syncthreads();

    // fc2 from normalized gA (registers), then overwrite gA
#pragma unroll
    for (int j = 0; j < 16; ++j) acc[j] = b2f[q * 16 + j];
#pragma unroll
    for (int k = 0; k < 64; ++k) {
        float gn = (gA[r][k] - mS[k]) * iS[k];
#pragma unroll
        for (int j = 0; j < 16; ++j) acc[j] += gn * w2s[k * 64 + q * 16 + j];
    }
    __syncthreads();
#pragma unroll
    for (int j = 0; j < 16; ++j) gA[r][q * 16 + j] = fmaxf(acc[j], 0.f);
    __syncthreads();

    if (t < 64) {
        float s = 0.f, s2 = 0.f;
        for (int rr = 0; rr < 256; ++rr) { float v = gA[rr][t]; s += v; s2 += v * v; }
        float m = s * (1.f / 256.f);
        float var = s2 * (1.f / 256.f) - m * m;
        mS[t] = m;
        iS[t] = rsqrtf(var + 1e-5f);
    }
    __syncthreads();

    if (q < 2) {
        float a = b3f[q];
#pragma unroll
        for (int k = 0; k < 64; ++k) {
            float gn = (gA[r][k] - mS[k]) * iS[k];
            a += gn * W3f[k * 2 + q];
        }
        ypred[r * 2 + q] = a;
    }
}

// ---------------------------------------------------------------------------
extern "C" void kernel_launch(void* const* d_in, const int* in_sizes, int n_in,
                              void* d_out, int out_size, void* d_ws, size_t ws_size,
                              hipStream_t stream) {
    const float* x    = (const float*)d_in[0];
    const int*   arow = (const int*)d_in[1];
    const int*   acol = (const int*)d_in[2];
    const float* aval = (const float*)d_in[3];
    const float* W1 = (const float*)d_in[4];
    const float* b1 = (const float*)d_in[5];
    const float* W2 = (const float*)d_in[6];
    const float* b2 = (const float*)d_in[7];
    const float* W3 = (const float*)d_in[8];
    const float* b3 = (const float*)d_in[9];
    const float* fc1W = (const float*)d_in[10];
    const float* fc1b = (const float*)d_in[11];
    const float* fc2W = (const float*)d_in[12];
    const float* fc2b = (const float*)d_in[13];
    const float* fc3W = (const float*)d_in[14];
    const float* fc3b = (const float*)d_in[15];

    char* w = (char*)d_ws;
    size_t off = 0;
    float* U = (float*)(w + off);  off += (size_t)Mrows * Hh * 4;   // 26.2 MB
    float* Z = (float*)(w + off);  off += (size_t)Mrows * Hh * 4;   // 26.2 MB
    int* counts  = (int*)(w + off); off += 1600;
    int* row_ptr = (int*)(w + off); off += 404 * 4;
    int* cursor  = (int*)(w + off); off += 1600;
    int* ci      = (int*)(w + off); off += NNZ * 4;
    float* cv    = (float*)(w + off); off += NNZ * 4;
    float* stats = (float*)(w + off); off += 1600 * 4;   // ssum1,ssq1,ssum2,ssq2
    float* ssum1 = stats, *ssq1 = stats + 400, *ssum2 = stats + 800, *ssq2 = stats + 1200;
    float* mean1 = (float*)(w + off); off += 1600;
    float* inv1  = (float*)(w + off); off += 1600;
    float* mean2 = (float*)(w + off); off += 1600;
    float* inv2  = (float*)(w + off); off += 1600;
    float* out1  = (float*)(w + off); off += Bb * Hh * 4;
    float* out2  = (float*)(w + off); off += Bb * Hh * 4;
    float* out3  = (float*)(w + off); off += Bb * Hh * 4;

    float* ypred = (float*)d_out;
    float* x3    = (float*)d_out + 512;

    // CSR build
    initk<<<2, 1024, 0, stream>>>(counts, stats);
    countk<<<(NNZ + 255) / 256, 256, 0, stream>>>(arow, counts);
    scank<<<1, 512, 0, stream>>>(counts, row_ptr, cursor);
    scatterk<<<(NNZ + 255) / 256, 256, 0, stream>>>(arow, acol, aval, cursor, ci, cv);

    // Layer 1
    gemm64<FIN, false><<<Mrows / 64, 256, 0, stream>>>(x, W1, U, nullptr, nullptr);
    aggk<true><<<Bb, 512, 0, stream>>>(U, row_ptr, ci, cv, b1, Z, ssum1, ssq1);
    finalize_stats<<<1, 512, 0, stream>>>(ssum1, ssq1, mean1, inv1);
    maxk<true><<<Bb, 256, 0, stream>>>(Z, mean1, inv1, out1);

    // Layer 2 (BN of layer 1 folded into GEMM A-side)
    gemm64<Hh, true><<<Mrows / 64, 256, 0, stream>>>(Z, W2, U, mean1, inv1);
    aggk<true><<<Bb, 512, 0, stream>>>(U, row_ptr, ci, cv, b2, Z, ssum2, ssq2);
    finalize_stats<<<1, 512, 0, stream>>>(ssum2, ssq2, mean2, inv2);
    maxk<true><<<Bb, 256, 0, stream>>>(Z, mean2, inv2, out2);

    // Layer 3 (no relu / no BN) -> x3 straight into d_out
    gemm64<Hh, true><<<Mrows / 64, 256, 0, stream>>>(Z, W3, U, mean2, inv2);
    aggk<false><<<Bb, 512, 0, stream>>>(U, row_ptr, ci, cv, b3, x3, nullptr, nullptr);
    maxk<false><<<Bb, 256, 0, stream>>>(x3, nullptr, nullptr, out3);

    // FC head
    headk<<<1, 1024, 0, stream>>>(out1, out2, out3, fc1W, fc1b, fc2W, fc2b,
                                  fc3W, fc3b, ypred);
}

// Round 2
// 612.777 us; speedup vs baseline: 2.3121x; 2.3121x over previous
//
#include <hip/hip_runtime.h>
#include <hip/hip_bf16.h>
#include <math.h>

// Problem constants
#define Bb   256
#define Nn   400
#define FIN  400
#define Hh   64
#define NNZ  16000
#define NNZ_PAD 18816          // 16000 + 400*7 padded slots, rounded up
#define Mrows (Bb*Nn)          // 102400
#define BH_COUNT 16384.0f      // B*H for BN3 stats

// ---------------------------------------------------------------------------
// init: zero CSR counts + BN stats accumulators + padded CSR arrays
// ---------------------------------------------------------------------------
__global__ void initk(int* __restrict__ counts, float* __restrict__ stats,
                      int* __restrict__ ci, float* __restrict__ cv) {
    int t = blockIdx.x * blockDim.x + threadIdx.x;
    if (t < Nn) counts[t] = 0;
    if (t < 1600) stats[t] = 0.f;   // ssum1, ssq1, ssum2, ssq2 (4 x 400)
    if (t < NNZ_PAD) { ci[t] = 0; cv[t] = 0.f; }
}

__global__ void countk(const int* __restrict__ rows, int* __restrict__ counts) {
    int i = blockIdx.x * blockDim.x + threadIdx.x;
    if (i < NNZ) atomicAdd(&counts[rows[i]], 1);
}

// single-block Hillis-Steele scan over 400 (padded 512) of counts rounded
// up to a multiple of 8 (so each CSR row length is a multiple of 8).
__global__ void scank(const int* __restrict__ counts, int* __restrict__ row_ptr,
                      int* __restrict__ cursor) {
    __shared__ int s[512];
    int t = threadIdx.x;
    int c = (t < Nn) ? ((counts[t] + 7) & ~7) : 0;
    s[t] = c;
    __syncthreads();
    for (int off = 1; off < 512; off <<= 1) {
        int v = (t >= off) ? s[t - off] : 0;
        __syncthreads();
        s[t] += v;
        __syncthreads();
    }
    if (t < Nn) { int excl = s[t] - c; row_ptr[t] = excl; cursor[t] = excl; }
    if (t == Nn - 1) row_ptr[Nn] = s[Nn - 1];
}

__global__ void scatterk(const int* __restrict__ rows, const int* __restrict__ cols,
                         const float* __restrict__ vals, int* __restrict__ cursor,
                         int* __restrict__ ci, float* __restrict__ cv) {
    int i = blockIdx.x * blockDim.x + threadIdx.x;
    if (i < NNZ) {
        int r = rows[i];
        int p = atomicAdd(&cursor[r], 1);
        ci[p] = cols[i];
        cv[p] = vals[i];
    }
}

// ---------------------------------------------------------------------------
// GEMM: C[M,64] = A[M,KT] @ W[KT,64], optional fused BN affine on A-side:
//   C = inv[r] * (A@W - mean[r]*colsum(W)),  r = row % 400
// Tile 64x64, 256 threads, 4x4 per thread, K-step 16.
// ---------------------------------------------------------------------------
template <int KT, bool AFFINE>
__global__ __launch_bounds__(256) void gemm64(
        const float* __restrict__ A, const float* __restrict__ W,
        float* __restrict__ C, const float* __restrict__ mean,
        const float* __restrict__ inv) {
    __shared__ float As[16][68];
    __shared__ float Bs[16][64];
    __shared__ float cs[64];
    const int t  = threadIdx.x;
    const int tx = t & 15, ty = t >> 4;
    const int m0 = blockIdx.x * 64;

    if (AFFINE) {
        if (t < 64) {
            float s = 0.f;
            for (int k = 0; k < KT; ++k) s += W[k * 64 + t];
            cs[t] = s;
        }
    }

    const int lr  = t >> 2;   // 0..63 A row
    const int lc4 = t & 3;    // float4 col (of 16)
    const int wk  = t >> 4;   // 0..15 W row
    const int wc4 = t & 15;   // float4 col (of 64)

    float acc[4][4];
#pragma unroll
    for (int i = 0; i < 4; ++i)
#pragma unroll
        for (int j = 0; j < 4; ++j) acc[i][j] = 0.f;

    for (int k0 = 0; k0 < KT; k0 += 16) {
        float4 av = *reinterpret_cast<const float4*>(
            &A[(size_t)(m0 + lr) * KT + k0 + lc4 * 4]);
        float4 wv = *reinterpret_cast<const float4*>(
            &W[(size_t)(k0 + wk) * 64 + wc4 * 4]);
        __syncthreads();
        As[lc4 * 4 + 0][lr] = av.x;
        As[lc4 * 4 + 1][lr] = av.y;
        As[lc4 * 4 + 2][lr] = av.z;
        As[lc4 * 4 + 3][lr] = av.w;
        *reinterpret_cast<float4*>(&Bs[wk][wc4 * 4]) = wv;
        __syncthreads();
#pragma unroll
        for (int k = 0; k < 16; ++k) {
            float4 a4 = *reinterpret_cast<const float4*>(&As[k][ty * 4]);
            float4 b4 = *reinterpret_cast<const float4*>(&Bs[k][tx * 4]);
            float a[4] = {a4.x, a4.y, a4.z, a4.w};
            float b[4] = {b4.x, b4.y, b4.z, b4.w};
#pragma unroll
            for (int i = 0; i < 4; ++i)
#pragma unroll
                for (int j = 0; j < 4; ++j) acc[i][j] += a[i] * b[j];
        }
    }

#pragma unroll
    for (int i = 0; i < 4; ++i) {
        int g = m0 + ty * 4 + i;
        float mm = 0.f, iv = 1.f;
        if (AFFINE) {
            int r = g % Nn;
            mm = mean[r];
            iv = inv[r];
        }
        float res[4];
#pragma unroll
        for (int j = 0; j < 4; ++j) {
            float u = acc[i][j];
            if (AFFINE) u = iv * (u - mm * cs[tx * 4 + j]);
            res[j] = u;
        }
        *reinterpret_cast<float4*>(&C[(size_t)g * 64 + tx * 4]) =
            make_float4(res[0], res[1], res[2], res[3]);
    }
}

// ---------------------------------------------------------------------------
// Sparse aggregation + bias + L2-normalize (+ relu + BN3 stat partials).
// One WAVE per output row (b, r); lane = feature h. No LDS: U rows come from
// L2 (b-major grid => ~20 active batches => ~2 MB/XCD working set).
// (ci,cv) for the row are loaded once, coalesced, into lane registers and
// broadcast via __shfl; 8 independent accumulators give 8 U-loads in flight.
// Row nnz counts are padded to a multiple of 8 (zero-valued entries).
// ---------------------------------------------------------------------------
template <bool RELU_STATS>
__global__ __launch_bounds__(256) void aggk(
        const float* __restrict__ U, const int* __restrict__ rp,
        const int* __restrict__ ci, const float* __restrict__ cv,
        const float* __restrict__ bias, float* __restrict__ Z,
        float* __restrict__ ssum, float* __restrict__ ssq) {
    const int b     = blockIdx.x / (Nn / 4);
    const int chunk = blockIdx.x % (Nn / 4);
    const int lane  = threadIdx.x & 63;
    const int wave  = threadIdx.x >> 6;
    const int r     = chunk * 4 + wave;
    const float* __restrict__ Ub = U + (size_t)b * Nn * Hh;

    const int s = rp[r], e = rp[r + 1];

    float acc[8];
    acc[0] = bias[lane];
#pragma unroll
    for (int u = 1; u < 8; ++u) acc[u] = 0.f;

    for (int j0 = s; j0 < e; j0 += 64) {
        int   c0 = 0;
        float v0 = 0.f;
        int idx = j0 + lane;
        if (idx < e) { c0 = ci[idx]; v0 = cv[idx]; }
        const int cnt = min(64, e - j0);   // multiple of 8
        for (int k = 0; k < cnt; k += 8) {
#pragma unroll
            for (int u = 0; u < 8; ++u) {
                int   c = __shfl(c0, k + u);
                float v = __shfl(v0, k + u);
                acc[u] += v * Ub[(size_t)c * Hh + lane];
            }
        }
    }

    float a = ((acc[0] + acc[1]) + (acc[2] + acc[3])) +
              ((acc[4] + acc[5]) + (acc[6] + acc[7]));
    float ss = a * a;
#pragma unroll
    for (int off = 32; off; off >>= 1) ss += __shfl_xor(ss, off);
    float z = a / fmaxf(sqrtf(ss), 1e-12f);
    if (RELU_STATS) z = fmaxf(z, 0.f);
    Z[((size_t)b * Nn + r) * Hh + lane] = z;
    if (RELU_STATS) {
        float s1 = z, s2 = z * z;
#pragma unroll
        for (int off = 32; off; off >>= 1) {
            s1 += __shfl_xor(s1, off);
            s2 += __shfl_xor(s2, off);
        }
        if (lane == 0) {
            atomicAdd(&ssum[r], s1);
            atomicAdd(&ssq[r], s2);
        }
    }
}

__global__ void finalize_stats(const float* __restrict__ ssum,
                               const float* __restrict__ ssq,
                               float* __restrict__ mean, float* __restrict__ inv) {
    int r = threadIdx.x;
    if (r < Nn) {
        float m = ssum[r] * (1.0f / BH_COUNT);
        float v = ssq[r] * (1.0f / BH_COUNT) - m * m;
        mean[r] = m;
        inv[r]  = rsqrtf(v + 1e-5f);
    }
}

// ---------------------------------------------------------------------------
// out[b,h] = max_r affine(Z[b,r,h])   (affine = BN3, or identity for layer 3)
// Grid: 256 blocks (b), 256 threads (4 r-groups x 64 h)
// ---------------------------------------------------------------------------
template <bool AFF>
__global__ __launch_bounds__(256) void maxk(
        const float* __restrict__ Z, const float* __restrict__ mean,
        const float* __restrict__ inv, float* __restrict__ out) {
    __shared__ float red[4][64];
    const int b  = blockIdx.x;
    const int h  = threadIdx.x & 63;
    const int rg = threadIdx.x >> 6;
    float best = -3.4e38f;
    for (int r = rg; r < Nn; r += 4) {
        float v = Z[((size_t)b * Nn + r) * Hh + h];
        if (AFF) v = (v - mean[r]) * inv[r];
        best = fmaxf(best, v);
    }
    red[rg][h] = best;
    __syncthreads();
    if (threadIdx.x < 64) {
        float m = fmaxf(fmaxf(red[0][threadIdx.x], red[1][threadIdx.x]),
                        fmaxf(red[2][threadIdx.x], red[3][threadIdx.x]));
        out[b * Hh + threadIdx.x] = m;
    }
}

// ---------------------------------------------------------------------------
// FC head: h=[out1|out2|out3] (256x192) -> fc1+relu+bn2 -> fc2+relu+bn2 -> fc3
// Single block, 1024 threads: thread (r = t>>2, q = t&3) owns 16 cols.
// ---------------------------------------------------------------------------
__global__ __launch_bounds__(1024) void headk(
        const float* __restrict__ out1, const float* __restrict__ out2,
        const float* __restrict__ out3,
        const float* __restrict__ W1f, const float* __restrict__ b1f,
        const float* __restrict__ W2f, const float* __restrict__ b2f,
        const float* __restrict__ W3f, const float* __restrict__ b3f,
        float* __restrict__ ypred) {
    __shared__ float gA[256][64];     // 64 KB activations
    __shared__ float w1s[192 * 64];   // 48 KB
    __shared__ float w2s[64 * 64];    // 16 KB
    __shared__ float mS[64], iS[64];
    const int t = threadIdx.x;
    const int r = t >> 2, q = t & 3;

    for (int i = t; i < 192 * 64; i += 1024) w1s[i] = W1f[i];
    for (int i = t; i < 64 * 64; i += 1024) w2s[i] = W2f[i];
    __syncthreads();

    float acc[16];
#pragma unroll
    for (int j = 0; j < 16; ++j) acc[j] = b1f[q * 16 + j];
    for (int k = 0; k < 192; ++k) {
        float hv = (k < 64) ? out1[r * 64 + k]
                 : (k < 128) ? out2[r * 64 + (k - 64)]
                             : out3[r * 64 + (k - 128)];
#pragma unroll
        for (int j = 0; j < 16; ++j) acc[j] += hv * w1s[k * 64 + q * 16 + j];
    }
#pragma unroll
    for (int j = 0; j < 16; ++j) gA[r][q * 16 + j] = fmaxf(acc[j], 0.f);
    __syncthreads();

    if (t < 64) {
        float s = 0.f, s2 = 0.f;
        for (int rr = 0; rr < 256; ++rr) { float v = gA[rr][t]; s += v; s2 += v * v; }
        float m = s * (1.f / 256.f);
        float var = s2 * (1.f / 256.f) - m * m;
        mS[t] = m;
        iS[t] = rsqrtf(var + 1e-5f);
    }
    __syncthreads();

    // fc2 from normalized gA (registers), then overwrite gA
#pragma unroll
    for (int j = 0; j < 16; ++j) acc[j] = b2f[q * 16 + j];
#pragma unroll
    for (int k = 0; k < 64; ++k) {
        float gn = (gA[r][k] - mS[k]) * iS[k];
#pragma unroll
        for (int j = 0; j < 16; ++j) acc[j] += gn * w2s[k * 64 + q * 16 + j];
    }
    __syncthreads();
#pragma unroll
    for (int j = 0; j < 16; ++j) gA[r][q * 16 + j] = fmaxf(acc[j], 0.f);
    __syncthreads();

    if (t < 64) {
        float s = 0.f, s2 = 0.f;
        for (int rr = 0; rr < 256; ++rr) { float v = gA[rr][t]; s += v; s2 += v * v; }
        float m = s * (1.f / 256.f);
        float var = s2 * (1.f / 256.f) - m * m;
        mS[t] = m;
        iS[t] = rsqrtf(var + 1e-5f);
    }
    __syncthreads();

    if (q < 2) {
        float a = b3f[q];
#pragma unroll
        for (int k = 0; k < 64; ++k) {
            float gn = (gA[r][k] - mS[k]) * iS[k];
            a += gn * W3f[k * 2 + q];
        }
        ypred[r * 2 + q] = a;
    }
}

// ---------------------------------------------------------------------------
extern "C" void kernel_launch(void* const* d_in, const int* in_sizes, int n_in,
                              void* d_out, int out_size, void* d_ws, size_t ws_size,
                              hipStream_t stream) {
    const float* x    = (const float*)d_in[0];
    const int*   arow = (const int*)d_in[1];
    const int*   acol = (const int*)d_in[2];
    const float* aval = (const float*)d_in[3];
    const float* W1 = (const float*)d_in[4];
    const float* b1 = (const float*)d_in[5];
    const float* W2 = (const float*)d_in[6];
    const float* b2 = (const float*)d_in[7];
    const float* W3 = (const float*)d_in[8];
    const float* b3 = (const float*)d_in[9];
    const float* fc1W = (const float*)d_in[10];
    const float* fc1b = (const float*)d_in[11];
    const float* fc2W = (const float*)d_in[12];
    const float* fc2b = (const float*)d_in[13];
    const float* fc3W = (const float*)d_in[14];
    const float* fc3b = (const float*)d_in[15];

    char* w = (char*)d_ws;
    size_t off = 0;
    float* U = (float*)(w + off);  off += (size_t)Mrows * Hh * 4;   // 26.2 MB
    float* Z = (float*)(w + off);  off += (size_t)Mrows * Hh * 4;   // 26.2 MB
    int* counts  = (int*)(w + off); off += 1600;
    int* row_ptr = (int*)(w + off); off += 404 * 4;
    int* cursor  = (int*)(w + off); off += 1600;
    int* ci      = (int*)(w + off); off += NNZ_PAD * 4;
    float* cv    = (float*)(w + off); off += NNZ_PAD * 4;
    float* stats = (float*)(w + off); off += 1600 * 4;   // ssum1,ssq1,ssum2,ssq2
    float* ssum1 = stats, *ssq1 = stats + 400, *ssum2 = stats + 800, *ssq2 = stats + 1200;
    float* mean1 = (float*)(w + off); off += 1600;
    float* inv1  = (float*)(w + off); off += 1600;
    float* mean2 = (float*)(w + off); off += 1600;
    float* inv2  = (float*)(w + off); off += 1600;
    float* out1  = (float*)(w + off); off += Bb * Hh * 4;
    float* out2  = (float*)(w + off); off += Bb * Hh * 4;
    float* out3  = (float*)(w + off); off += Bb * Hh * 4;

    float* ypred = (float*)d_out;
    float* x3    = (float*)d_out + 512;

    // CSR build (rows padded to multiple of 8 with zero entries)
    initk<<<(NNZ_PAD + 1023) / 1024, 1024, 0, stream>>>(counts, stats, ci, cv);
    countk<<<(NNZ + 255) / 256, 256, 0, stream>>>(arow, counts);
    scank<<<1, 512, 0, stream>>>(counts, row_ptr, cursor);
    scatterk<<<(NNZ + 255) / 256, 256, 0, stream>>>(arow, acol, aval, cursor, ci, cv);

    const int AGG_GRID = Bb * (Nn / 4);   // one wave per (b, row)

    // Layer 1
    gemm64<FIN, false><<<Mrows / 64, 256, 0, stream>>>(x, W1, U, nullptr, nullptr);
    aggk<true><<<AGG_GRID, 256, 0, stream>>>(U, row_ptr, ci, cv, b1, Z, ssum1, ssq1);
    finalize_stats<<<1, 512, 0, stream>>>(ssum1, ssq1, mean1, inv1);
    maxk<true><<<Bb, 256, 0, stream>>>(Z, mean1, inv1, out1);

    // Layer 2 (BN of layer 1 folded into GEMM A-side)
    gemm64<Hh, true><<<Mrows / 64, 256, 0, stream>>>(Z, W2, U, mean1, inv1);
    aggk<true><<<AGG_GRID, 256, 0, stream>>>(U, row_ptr, ci, cv, b2, Z, ssum2, ssq2);
    finalize_stats<<<1, 512, 0, stream>>>(ssum2, ssq2, mean2, inv2);
    maxk<true><<<Bb, 256, 0, stream>>>(Z, mean2, inv2, out2);

    // Layer 3 (no relu / no BN) -> x3 straight into d_out
    gemm64<Hh, true><<<Mrows / 64, 256, 0, stream>>>(Z, W3, U, mean2, inv2);
    aggk<false><<<AGG_GRID, 256, 0, stream>>>(U, row_ptr, ci, cv, b3, x3, nullptr, nullptr);
    maxk<false><<<Bb, 256, 0, stream>>>(x3, nullptr, nullptr, out3);

    // FC head
    headk<<<1, 1024, 0, stream>>>(out1, out2, out3, fc1W, fc1b, fc2W, fc2b,
                                  fc3W, fc3b, ypred);
}

// Round 3
// 436.632 us; speedup vs baseline: 3.2449x; 1.4034x over previous
//
#include <hip/hip_runtime.h>
#include <hip/hip_bf16.h>
#include <math.h>

// Problem constants
#define Bb   256
#define Nn   400
#define FIN  400
#define Hh   64
#define NNZ  16000
#define Mrows (Bb*Nn)          // 102400
#define KP   416               // K padded to 13*32 for MFMA
#define UPAD 420               // LDS row pad (bank-conflict-free: gcd trick)
#define BH_COUNT 16384.0f      // B*H for BN3 stats

typedef unsigned int  u32x2 __attribute__((ext_vector_type(2)));
typedef unsigned int  u32x4 __attribute__((ext_vector_type(4)));
typedef __bf16        bf16x8 __attribute__((ext_vector_type(8)));
typedef float         f32x4 __attribute__((ext_vector_type(4)));

__device__ __forceinline__ unsigned int f2bf(float x) {
    unsigned int u = __builtin_bit_cast(unsigned int, x);
    return (u + 0x7FFFu + ((u >> 16) & 1u)) >> 16;   // RNE
}

// ---------------------------------------------------------------------------
// init: zero dense-A f32 accumulator + BN stats accumulators
// ---------------------------------------------------------------------------
__global__ void initk(float* __restrict__ Adf, float* __restrict__ stats) {
    int t = blockIdx.x * blockDim.x + threadIdx.x;
    if (t < Nn * KP) Adf[t] = 0.f;
    if (t < 1600) stats[t] = 0.f;   // ssum1, ssq1, ssum2, ssq2 (4 x 400)
}

__global__ void scatAk(const int* __restrict__ rows, const int* __restrict__ cols,
                       const float* __restrict__ vals, float* __restrict__ Adf) {
    int i = blockIdx.x * blockDim.x + threadIdx.x;
    if (i < NNZ) atomicAdd(&Adf[rows[i] * KP + cols[i]], vals[i]);
}

__global__ void cvtAk(const float* __restrict__ Adf, unsigned short* __restrict__ Adbf) {
    int i = blockIdx.x * blockDim.x + threadIdx.x;
    if (i < Nn * KP) Adbf[i] = (unsigned short)f2bf(Adf[i]);
}

// ---------------------------------------------------------------------------
// GEMM: C[M,64](bf16) = A[M,KT] @ W[KT,64], optional fused BN affine (A-side):
//   C = inv[r] * (A@W - mean[r]*colsum(W)),  r = row % 400
// Tile 64x64, 256 threads, 4x4 per thread, K-step 16.  f32 vector math.
// ---------------------------------------------------------------------------
template <int KT, bool AFFINE>
__global__ __launch_bounds__(256) void gemm64(
        const float* __restrict__ A, const float* __restrict__ W,
        unsigned short* __restrict__ C, const float* __restrict__ mean,
        const float* __restrict__ inv) {
    __shared__ float As[16][68];
    __shared__ float Bs[16][64];
    __shared__ float cs[64];
    const int t  = threadIdx.x;
    const int tx = t & 15, ty = t >> 4;
    const int m0 = blockIdx.x * 64;

    if (AFFINE) {
        if (t < 64) {
            float s = 0.f;
            for (int k = 0; k < KT; ++k) s += W[k * 64 + t];
            cs[t] = s;
        }
    }

    const int lr  = t >> 2;   // 0..63 A row
    const int lc4 = t & 3;    // float4 col (of 16)
    const int wk  = t >> 4;   // 0..15 W row
    const int wc4 = t & 15;   // float4 col (of 64)

    float acc[4][4];
#pragma unroll
    for (int i = 0; i < 4; ++i)
#pragma unroll
        for (int j = 0; j < 4; ++j) acc[i][j] = 0.f;

    for (int k0 = 0; k0 < KT; k0 += 16) {
        float4 av = *reinterpret_cast<const float4*>(
            &A[(size_t)(m0 + lr) * KT + k0 + lc4 * 4]);
        float4 wv = *reinterpret_cast<const float4*>(
            &W[(size_t)(k0 + wk) * 64 + wc4 * 4]);
        __syncthreads();
        As[lc4 * 4 + 0][lr] = av.x;
        As[lc4 * 4 + 1][lr] = av.y;
        As[lc4 * 4 + 2][lr] = av.z;
        As[lc4 * 4 + 3][lr] = av.w;
        *reinterpret_cast<float4*>(&Bs[wk][wc4 * 4]) = wv;
        __syncthreads();
#pragma unroll
        for (int k = 0; k < 16; ++k) {
            float4 a4 = *reinterpret_cast<const float4*>(&As[k][ty * 4]);
            float4 b4 = *reinterpret_cast<const float4*>(&Bs[k][tx * 4]);
            float a[4] = {a4.x, a4.y, a4.z, a4.w};
            float b[4] = {b4.x, b4.y, b4.z, b4.w};
#pragma unroll
            for (int i = 0; i < 4; ++i)
#pragma unroll
                for (int j = 0; j < 4; ++j) acc[i][j] += a[i] * b[j];
        }
    }

#pragma unroll
    for (int i = 0; i < 4; ++i) {
        int g = m0 + ty * 4 + i;
        float mm = 0.f, iv = 1.f;
        if (AFFINE) {
            int r = g % Nn;
            mm = mean[r];
            iv = inv[r];
        }
        unsigned int pk[2];
        float res[4];
#pragma unroll
        for (int j = 0; j < 4; ++j) {
            float u = acc[i][j];
            if (AFFINE) u = iv * (u - mm * cs[tx * 4 + j]);
            res[j] = u;
        }
        pk[0] = f2bf(res[0]) | (f2bf(res[1]) << 16);
        pk[1] = f2bf(res[2]) | (f2bf(res[3]) << 16);
        *reinterpret_cast<u32x2*>(&C[(size_t)g * 64 + tx * 4]) = u32x2{pk[0], pk[1]};
    }
}

// ---------------------------------------------------------------------------
// Dense MFMA aggregation:  Z[b] = normalize(A_dense @ U[b] + bias) (+relu+stats)
// One block per batch b, 256 threads = 4 waves.
// LDS: U[b]^T as bf16 [64 cols][UPAD k] (rows k>=400 zeroed).
// Wave w owns M-tiles t = w, w+4, ... (25 tiles of 16 rows); per K-step the
// 4 B-frags (one per 16-col block) are read once and reused for all tiles.
// mfma_f32_16x16x32_bf16; C/D layout: col=lane&15, row=(lane>>4)*4+reg.
// ---------------------------------------------------------------------------
template <bool RELU_STATS>
__global__ __launch_bounds__(256) void aggmm(
        const unsigned short* __restrict__ Ad,   // [400][416] bf16 bits
        const unsigned short* __restrict__ Ubf,  // [B*400][64] bf16 bits
        const float* __restrict__ bias,
        float* __restrict__ Z,                   // [B*400][64] f32
        float* __restrict__ ssum, float* __restrict__ ssq) {
    __shared__ unsigned short Us[64 * UPAD];     // 53760 B
    const int b    = blockIdx.x;
    const int tid  = threadIdx.x;
    const int lane = tid & 63;
    const int wv   = tid >> 6;
    const int cl   = lane & 15;        // col within 16-block / A row within tile
    const int g    = lane >> 4;        // k-subgroup (A/B) and row-group (C)

    // ---- stage U[b]^T into LDS (bf16) ----
    const unsigned short* Ub = Ubf + (size_t)b * Nn * Hh;
    for (int seg = tid; seg < Nn * 8; seg += 256) {       // 8 segs of 8 cols per row
        int r = seg >> 3, c0 = (seg & 7) * 8;
        u32x4 v = *reinterpret_cast<const u32x4*>(&Ub[r * 64 + c0]);
#pragma unroll
        for (int j = 0; j < 8; ++j) {
            unsigned short h = (unsigned short)((v[j >> 1] >> (16 * (j & 1))) & 0xFFFFu);
            Us[(c0 + j) * UPAD + r] = h;
        }
    }
    for (int i = tid; i < 64 * (UPAD - Nn); i += 256) {   // zero k = 400..UPAD-1
        int c = i / (UPAD - Nn), k = Nn + i % (UPAD - Nn);
        Us[c * UPAD + k] = 0;
    }
    __syncthreads();

    f32x4 acc[7][4];
#pragma unroll
    for (int i = 0; i < 7; ++i)
#pragma unroll
        for (int n = 0; n < 4; ++n) acc[i][n] = f32x4{0.f, 0.f, 0.f, 0.f};

    for (int k0 = 0; k0 < KP; k0 += 32) {
        const int kk = k0 + g * 8;
        bf16x8 bf[4];
#pragma unroll
        for (int n = 0; n < 4; ++n) {
            int col = n * 16 + cl;
            const unsigned short* p = &Us[col * UPAD + kk];
            u32x2 lo = *reinterpret_cast<const u32x2*>(p);
            u32x2 hi = *reinterpret_cast<const u32x2*>(p + 4);
            u32x4 w; w[0] = lo[0]; w[1] = lo[1]; w[2] = hi[0]; w[3] = hi[1];
            bf[n] = __builtin_bit_cast(bf16x8, w);
        }
#pragma unroll
        for (int i = 0; i < 7; ++i) {
            int t = wv + 4 * i;
            if (t < 25) {
                int row = t * 16 + cl;
                u32x4 ar = *reinterpret_cast<const u32x4*>(&Ad[(size_t)row * KP + kk]);
                bf16x8 af = __builtin_bit_cast(bf16x8, ar);
#pragma unroll
                for (int n = 0; n < 4; ++n)
                    acc[i][n] = __builtin_amdgcn_mfma_f32_16x16x32_bf16(
                        af, bf[n], acc[i][n], 0, 0, 0);
            }
        }
    }

    float bv[4];
#pragma unroll
    for (int n = 0; n < 4; ++n) bv[n] = bias[n * 16 + cl];

#pragma unroll
    for (int i = 0; i < 7; ++i) {
        int t = wv + 4 * i;
        if (t < 25) {
            float y[4][4];
#pragma unroll
            for (int n = 0; n < 4; ++n)
#pragma unroll
                for (int r = 0; r < 4; ++r) y[n][r] = acc[i][n][r] + bv[n];

            float pss[4];
#pragma unroll
            for (int r = 0; r < 4; ++r)
                pss[r] = y[0][r]*y[0][r] + y[1][r]*y[1][r] +
                         y[2][r]*y[2][r] + y[3][r]*y[3][r];
#pragma unroll
            for (int m = 1; m < 16; m <<= 1)
#pragma unroll
                for (int r = 0; r < 4; ++r) pss[r] += __shfl_xor(pss[r], m);

            float rin[4];
#pragma unroll
            for (int r = 0; r < 4; ++r)
                rin[r] = 1.f / fmaxf(sqrtf(pss[r]), 1e-12f);

#pragma unroll
            for (int n = 0; n < 4; ++n)
#pragma unroll
                for (int r = 0; r < 4; ++r) {
                    float z = y[n][r] * rin[r];
                    if (RELU_STATS) z = fmaxf(z, 0.f);
                    y[n][r] = z;
                    int row = t * 16 + g * 4 + r;
                    Z[((size_t)b * Nn + row) * Hh + n * 16 + cl] = z;
                }

            if (RELU_STATS) {
                float s1[4], s2[4];
#pragma unroll
                for (int r = 0; r < 4; ++r) {
                    s1[r] = y[0][r] + y[1][r] + y[2][r] + y[3][r];
                    s2[r] = y[0][r]*y[0][r] + y[1][r]*y[1][r] +
                            y[2][r]*y[2][r] + y[3][r]*y[3][r];
                }
#pragma unroll
                for (int m = 1; m < 16; m <<= 1)
#pragma unroll
                    for (int r = 0; r < 4; ++r) {
                        s1[r] += __shfl_xor(s1[r], m);
                        s2[r] += __shfl_xor(s2[r], m);
                    }
                if (cl == 0) {
#pragma unroll
                    for (int r = 0; r < 4; ++r) {
                        int row = t * 16 + g * 4 + r;
                        atomicAdd(&ssum[row], s1[r]);
                        atomicAdd(&ssq[row],  s2[r]);
                    }
                }
            }
        }
    }
}

__global__ void finalize_stats(const float* __restrict__ ssum,
                               const float* __restrict__ ssq,
                               float* __restrict__ mean, float* __restrict__ inv) {
    int r = threadIdx.x;
    if (r < Nn) {
        float m = ssum[r] * (1.0f / BH_COUNT);
        float v = ssq[r] * (1.0f / BH_COUNT) - m * m;
        mean[r] = m;
        inv[r]  = rsqrtf(v + 1e-5f);
    }
}

// ---------------------------------------------------------------------------
// out[b,h] = max_r affine(Z[b,r,h])   (affine = BN3, or identity for layer 3)
// ---------------------------------------------------------------------------
template <bool AFF>
__global__ __launch_bounds__(256) void maxk(
        const float* __restrict__ Z, const float* __restrict__ mean,
        const float* __restrict__ inv, float* __restrict__ out) {
    __shared__ float red[4][64];
    const int b  = blockIdx.x;
    const int h  = threadIdx.x & 63;
    const int rg = threadIdx.x >> 6;
    float best = -3.4e38f;
    for (int r = rg; r < Nn; r += 4) {
        float v = Z[((size_t)b * Nn + r) * Hh + h];
        if (AFF) v = (v - mean[r]) * inv[r];
        best = fmaxf(best, v);
    }
    red[rg][h] = best;
    __syncthreads();
    if (threadIdx.x < 64) {
        float m = fmaxf(fmaxf(red[0][threadIdx.x], red[1][threadIdx.x]),
                        fmaxf(red[2][threadIdx.x], red[3][threadIdx.x]));
        out[b * Hh + threadIdx.x] = m;
    }
}

// ---------------------------------------------------------------------------
// FC head: h=[out1|out2|out3] (256x192) -> fc1+relu+bn2 -> fc2+relu+bn2 -> fc3
// ---------------------------------------------------------------------------
__global__ __launch_bounds__(1024) void headk(
        const float* __restrict__ out1, const float* __restrict__ out2,
        const float* __restrict__ out3,
        const float* __restrict__ W1f, const float* __restrict__ b1f,
        const float* __restrict__ W2f, const float* __restrict__ b2f,
        const float* __restrict__ W3f, const float* __restrict__ b3f,
        float* __restrict__ ypred) {
    __shared__ float gA[256][64];     // 64 KB activations
    __shared__ float w1s[192 * 64];   // 48 KB
    __shared__ float w2s[64 * 64];    // 16 KB
    __shared__ float mS[64], iS[64];
    const int t = threadIdx.x;
    const int r = t >> 2, q = t & 3;

    for (int i = t; i < 192 * 64; i += 1024) w1s[i] = W1f[i];
    for (int i = t; i < 64 * 64; i += 1024) w2s[i] = W2f[i];
    __syncthreads();

    float acc[16];
#pragma unroll
    for (int j = 0; j < 16; ++j) acc[j] = b1f[q * 16 + j];
    for (int k = 0; k < 192; ++k) {
        float hv = (k < 64) ? out1[r * 64 + k]
                 : (k < 128) ? out2[r * 64 + (k - 64)]
                             : out3[r * 64 + (k - 128)];
#pragma unroll
        for (int j = 0; j < 16; ++j) acc[j] += hv * w1s[k * 64 + q * 16 + j];
    }
#pragma unroll
    for (int j = 0; j < 16; ++j) gA[r][q * 16 + j] = fmaxf(acc[j], 0.f);
    __syncthreads();

    if (t < 64) {
        float s = 0.f, s2 = 0.f;
        for (int rr = 0; rr < 256; ++rr) { float v = gA[rr][t]; s += v; s2 += v * v; }
        float m = s * (1.f / 256.f);
        float var = s2 * (1.f / 256.f) - m * m;
        mS[t] = m;
        iS[t] = rsqrtf(var + 1e-5f);
    }
    __syncthreads();

#pragma unroll
    for (int j = 0; j < 16; ++j) acc[j] = b2f[q * 16 + j];
#pragma unroll
    for (int k = 0; k < 64; ++k) {
        float gn = (gA[r][k] - mS[k]) * iS[k];
#pragma unroll
        for (int j = 0; j < 16; ++j) acc[j] += gn * w2s[k * 64 + q * 16 + j];
    }
    __syncthreads();
#pragma unroll
    for (int j = 0; j < 16; ++j) gA[r][q * 16 + j] = fmaxf(acc[j], 0.f);
    __syncthreads();

    if (t < 64) {
        float s = 0.f, s2 = 0.f;
        for (int rr = 0; rr < 256; ++rr) { float v = gA[rr][t]; s += v; s2 += v * v; }
        float m = s * (1.f / 256.f);
        float var = s2 * (1.f / 256.f) - m * m;
        mS[t] = m;
        iS[t] = rsqrtf(var + 1e-5f);
    }
    __syncthreads();

    if (q < 2) {
        float a = b3f[q];
#pragma unroll
        for (int k = 0; k < 64; ++k) {
            float gn = (gA[r][k] - mS[k]) * iS[k];
            a += gn * W3f[k * 2 + q];
        }
        ypred[r * 2 + q] = a;
    }
}

// ---------------------------------------------------------------------------
extern "C" void kernel_launch(void* const* d_in, const int* in_sizes, int n_in,
                              void* d_out, int out_size, void* d_ws, size_t ws_size,
                              hipStream_t stream) {
    const float* x    = (const float*)d_in[0];
    const int*   arow = (const int*)d_in[1];
    const int*   acol = (const int*)d_in[2];
    const float* aval = (const float*)d_in[3];
    const float* W1 = (const float*)d_in[4];
    const float* b1 = (const float*)d_in[5];
    const float* W2 = (const float*)d_in[6];
    const float* b2 = (const float*)d_in[7];
    const float* W3 = (const float*)d_in[8];
    const float* b3 = (const float*)d_in[9];
    const float* fc1W = (const float*)d_in[10];
    const float* fc1b = (const float*)d_in[11];
    const float* fc2W = (const float*)d_in[12];
    const float* fc2b = (const float*)d_in[13];
    const float* fc3W = (const float*)d_in[14];
    const float* fc3b = (const float*)d_in[15];

    char* w = (char*)d_ws;
    size_t off = 0;
    float* Adf = (float*)(w + off);            off += (size_t)Nn * KP * 4;     // 666 KB
    unsigned short* Adbf = (unsigned short*)(w + off); off += (size_t)Nn * KP * 2; // 333 KB
    unsigned short* Ubf  = (unsigned short*)(w + off); off += (size_t)Mrows * Hh * 2; // 13.1 MB
    float* Z = (float*)(w + off);              off += (size_t)Mrows * Hh * 4;  // 26.2 MB
    float* stats = (float*)(w + off);          off += 1600 * 4;
    float* ssum1 = stats, *ssq1 = stats + 400, *ssum2 = stats + 800, *ssq2 = stats + 1200;
    float* mean1 = (float*)(w + off); off += 1600;
    float* inv1  = (float*)(w + off); off += 1600;
    float* mean2 = (float*)(w + off); off += 1600;
    float* inv2  = (float*)(w + off); off += 1600;
    float* out1  = (float*)(w + off); off += Bb * Hh * 4;
    float* out2  = (float*)(w + off); off += Bb * Hh * 4;
    float* out3  = (float*)(w + off); off += Bb * Hh * 4;

    float* ypred = (float*)d_out;
    float* x3    = (float*)d_out + 512;

    // Densify adjacency -> bf16 [400][416]
    initk<<<(Nn * KP + 1023) / 1024, 1024, 0, stream>>>(Adf, stats);
    scatAk<<<(NNZ + 255) / 256, 256, 0, stream>>>(arow, acol, aval, Adf);
    cvtAk<<<(Nn * KP + 1023) / 1024, 1024, 0, stream>>>(Adf, Adbf);

    // Layer 1
    gemm64<FIN, false><<<Mrows / 64, 256, 0, stream>>>(x, W1, Ubf, nullptr, nullptr);
    aggmm<true><<<Bb, 256, 0, stream>>>(Adbf, Ubf, b1, Z, ssum1, ssq1);
    finalize_stats<<<1, 512, 0, stream>>>(ssum1, ssq1, mean1, inv1);
    maxk<true><<<Bb, 256, 0, stream>>>(Z, mean1, inv1, out1);

    // Layer 2 (BN of layer 1 folded into GEMM A-side)
    gemm64<Hh, true><<<Mrows / 64, 256, 0, stream>>>(Z, W2, Ubf, mean1, inv1);
    aggmm<true><<<Bb, 256, 0, stream>>>(Adbf, Ubf, b2, Z, ssum2, ssq2);
    finalize_stats<<<1, 512, 0, stream>>>(ssum2, ssq2, mean2, inv2);
    maxk<true><<<Bb, 256, 0, stream>>>(Z, mean2, inv2, out2);

    // Layer 3 (no relu / no BN) -> x3 straight into d_out
    gemm64<Hh, true><<<Mrows / 64, 256, 0, stream>>>(Z, W3, Ubf, mean2, inv2);
    aggmm<false><<<Bb, 256, 0, stream>>>(Adbf, Ubf, b3, x3, nullptr, nullptr);
    maxk<false><<<Bb, 256, 0, stream>>>(x3, nullptr, nullptr, out3);

    // FC head
    headk<<<1, 1024, 0, stream>>>(out1, out2, out3, fc1W, fc1b, fc2W, fc2b,
                                  fc3W, fc3b, ypred);
}

// Round 5
// 381.821 us; speedup vs baseline: 3.7107x; 1.1436x over previous
//
#include <hip/hip_runtime.h>
#include <hip/hip_bf16.h>
#include <math.h>

// Problem constants
#define Bb   256
#define Nn   400
#define FIN  400
#define Hh   64
#define NNZ  16000
#define Mrows (Bb*Nn)          // 102400
#define KP   416               // A-dense K padded to 13*32 for MFMA
#define UPAD 420               // aggmm LDS row pad
#define BH_COUNT 16384.0f      // B*H for BN3 stats

typedef unsigned int  u32x2 __attribute__((ext_vector_type(2)));
typedef unsigned int  u32x4 __attribute__((ext_vector_type(4)));
typedef __bf16        bf16x8 __attribute__((ext_vector_type(8)));
typedef float         f32x4 __attribute__((ext_vector_type(4)));

__device__ __forceinline__ unsigned int f2bf(float x) {
    unsigned int u = __builtin_bit_cast(unsigned int, x);
    return (u + 0x7FFFu + ((u >> 16) & 1u)) >> 16;   // RNE
}
__device__ __forceinline__ float bf2f(unsigned int h) {
    unsigned int u = h << 16;
    return __builtin_bit_cast(float, u);
}

// ---------------------------------------------------------------------------
// init: zero dense-A f32 accumulator + BN stats accumulators
// ---------------------------------------------------------------------------
__global__ void initk(float* __restrict__ Adf, float* __restrict__ stats) {
    int t = blockIdx.x * blockDim.x + threadIdx.x;
    if (t < Nn * KP) Adf[t] = 0.f;
    if (t < 1600) stats[t] = 0.f;   // ssum1, ssq1, ssum2, ssq2 (4 x 400)
}

__global__ void scatAk(const int* __restrict__ rows, const int* __restrict__ cols,
                       const float* __restrict__ vals, float* __restrict__ Adf) {
    int i = blockIdx.x * blockDim.x + threadIdx.x;
    if (i < NNZ) atomicAdd(&Adf[rows[i] * KP + cols[i]], vals[i]);
}

__global__ void cvtAk(const float* __restrict__ Adf, unsigned short* __restrict__ Adbf) {
    int i = blockIdx.x * blockDim.x + threadIdx.x;
    if (i < Nn * KP) Adbf[i] = (unsigned short)f2bf(Adf[i]);
}

// ---------------------------------------------------------------------------
// Split-precision MFMA GEMM:  C[M,64](bf16) = A[M,KT](f32) @ W[KT,64](f32)
// A = A_hi + A_lo, W = W_hi + W_lo (bf16 pairs); 3 MFMAs per step:
//   acc += Ah*Wh + Ah*Wl + Al*Wh   (error ~2^-16 rel, f32-grade)
// Optional fused A-side BN affine epilogue:
//   C = inv[r]*(A@W - mean[r]*colsum(W)), r = row % 400
// 8 waves x 16 rows = 128 rows/block. W^T hi/lo staged in LDS bf16 [64][KPADT].
// mfma_f32_16x16x32_bf16; A-frag: row=lane&15, k=(lane>>4)*8+j;
// C/D: col=lane&15, row=(lane>>4)*4+reg.
// ---------------------------------------------------------------------------
template <int KT, bool AFFINE>
__global__ __launch_bounds__(512) void xg(
        const float* __restrict__ A, const float* __restrict__ W,
        unsigned short* __restrict__ C, const float* __restrict__ mean,
        const float* __restrict__ inv) {
    constexpr int KPADT = (KT == 400) ? 424 : 72;   // bytes%16==0, 2-way banks
    constexpr int NSTEP = (KT + 31) / 32;
    __shared__ unsigned short Wh[64 * KPADT];
    __shared__ unsigned short Wl[64 * KPADT];
    __shared__ float cs[64];
    const int tid  = threadIdx.x;
    const int wv   = tid >> 6;      // 0..7
    const int lane = tid & 63;
    const int cl   = lane & 15;
    const int g    = lane >> 4;
    const int m0   = blockIdx.x * 128;

    // stage W^T hi/lo (bf16) into LDS
    for (int i = tid; i < KT * 64; i += 512) {
        int k = i >> 6, c = i & 63;
        float w = W[i];
        unsigned int hb = f2bf(w);
        Wh[c * KPADT + k] = (unsigned short)hb;
        Wl[c * KPADT + k] = (unsigned short)f2bf(w - bf2f(hb));
    }
    for (int i = tid; i < 64 * (KPADT - KT); i += 512) {
        int c = i / (KPADT - KT), k = KT + i % (KPADT - KT);
        Wh[c * KPADT + k] = 0;
        Wl[c * KPADT + k] = 0;
    }
    if (AFFINE) {
        if (tid < 64) {
            float s = 0.f;
            for (int k = 0; k < KT; ++k) s += W[k * 64 + tid];
            cs[tid] = s;
        }
    }
    __syncthreads();

    const int arow = m0 + wv * 16 + cl;

    f32x4 acc[4];
#pragma unroll
    for (int n = 0; n < 4; ++n) acc[n] = f32x4{0.f, 0.f, 0.f, 0.f};

    for (int s = 0; s < NSTEP; ++s) {
        const int kk = s * 32 + g * 8;
        float av[8];
#pragma unroll
        for (int j = 0; j < 8; ++j) av[j] = 0.f;
        if (kk < KT) {
            const float* p = &A[(size_t)arow * KT + kk];
            float4 lo = *reinterpret_cast<const float4*>(p);
            float4 hi = *reinterpret_cast<const float4*>(p + 4);
            av[0] = lo.x; av[1] = lo.y; av[2] = lo.z; av[3] = lo.w;
            av[4] = hi.x; av[5] = hi.y; av[6] = hi.z; av[7] = hi.w;
        }
        u32x4 ahw, alw;
#pragma unroll
        for (int j = 0; j < 4; ++j) {
            unsigned int h0 = f2bf(av[2 * j]);
            unsigned int h1 = f2bf(av[2 * j + 1]);
            unsigned int l0 = f2bf(av[2 * j]     - bf2f(h0));
            unsigned int l1 = f2bf(av[2 * j + 1] - bf2f(h1));
            ahw[j] = h0 | (h1 << 16);
            alw[j] = l0 | (l1 << 16);
        }
        bf16x8 ah = __builtin_bit_cast(bf16x8, ahw);
        bf16x8 al = __builtin_bit_cast(bf16x8, alw);
#pragma unroll
        for (int n = 0; n < 4; ++n) {
            const int co = (n * 16 + cl) * KPADT + kk;
            u32x4 bhw = *reinterpret_cast<const u32x4*>(&Wh[co]);
            u32x4 blw = *reinterpret_cast<const u32x4*>(&Wl[co]);
            bf16x8 bh = __builtin_bit_cast(bf16x8, bhw);
            bf16x8 bl = __builtin_bit_cast(bf16x8, blw);
            acc[n] = __builtin_amdgcn_mfma_f32_16x16x32_bf16(ah, bh, acc[n], 0, 0, 0);
            acc[n] = __builtin_amdgcn_mfma_f32_16x16x32_bf16(ah, bl, acc[n], 0, 0, 0);
            acc[n] = __builtin_amdgcn_mfma_f32_16x16x32_bf16(al, bh, acc[n], 0, 0, 0);
        }
    }

#pragma unroll
    for (int r = 0; r < 4; ++r) {
        const int row = m0 + wv * 16 + g * 4 + r;
        float mm = 0.f, iv = 1.f;
        if (AFFINE) {
            int node = row % Nn;
            mm = mean[node];
            iv = inv[node];
        }
#pragma unroll
        for (int n = 0; n < 4; ++n) {
            float y = acc[n][r];
            if (AFFINE) y = iv * (y - mm * cs[n * 16 + cl]);
            C[(size_t)row * Hh + n * 16 + cl] = (unsigned short)f2bf(y);
        }
    }
}

// ---------------------------------------------------------------------------
// Dense MFMA aggregation:  Z[b] = normalize(A_dense @ U[b] + bias)  (f32 out)
//   RELU_STATS: + relu + BN3 stat atomics; else: fused column-max -> outmax.
// One block per batch b, 256 threads = 4 waves. U[b]^T staged in LDS bf16.
// ---------------------------------------------------------------------------
template <bool RELU_STATS>
__global__ __launch_bounds__(256) void aggmm(
        const unsigned short* __restrict__ Ad,   // [400][416] bf16 bits
        const unsigned short* __restrict__ Ubf,  // [B*400][64] bf16 bits
        const float* __restrict__ bias,
        float* __restrict__ Zout,                // [B*400][64] f32
        float* __restrict__ ssum, float* __restrict__ ssq,
        float* __restrict__ outmax) {            // [B][64] (only !RELU_STATS)
    __shared__ unsigned short Us[64 * UPAD];     // 53760 B
    const int b    = blockIdx.x;
    const int tid  = threadIdx.x;
    const int lane = tid & 63;
    const int wv   = tid >> 6;
    const int cl   = lane & 15;
    const int g    = lane >> 4;

    // ---- stage U[b]^T into LDS (bf16) ----
    const unsigned short* Ub = Ubf + (size_t)b * Nn * Hh;
    for (int seg = tid; seg < Nn * 8; seg += 256) {       // 8 segs of 8 cols per row
        int r = seg >> 3, c0 = (seg & 7) * 8;
        u32x4 v = *reinterpret_cast<const u32x4*>(&Ub[r * 64 + c0]);
#pragma unroll
        for (int j = 0; j < 8; ++j) {
            unsigned short h = (unsigned short)((v[j >> 1] >> (16 * (j & 1))) & 0xFFFFu);
            Us[(c0 + j) * UPAD + r] = h;
        }
    }
    for (int i = tid; i < 64 * (UPAD - Nn); i += 256) {   // zero k = 400..UPAD-1
        int c = i / (UPAD - Nn), k = Nn + i % (UPAD - Nn);
        Us[c * UPAD + k] = 0;
    }
    __syncthreads();

    f32x4 acc[7][4];
#pragma unroll
    for (int i = 0; i < 7; ++i)
#pragma unroll
        for (int n = 0; n < 4; ++n) acc[i][n] = f32x4{0.f, 0.f, 0.f, 0.f};

    for (int k0 = 0; k0 < KP; k0 += 32) {
        const int kk = k0 + g * 8;
        bf16x8 bf[4];
#pragma unroll
        for (int n = 0; n < 4; ++n) {
            int col = n * 16 + cl;
            const unsigned short* p = &Us[col * UPAD + kk];
            u32x2 lo = *reinterpret_cast<const u32x2*>(p);
            u32x2 hi = *reinterpret_cast<const u32x2*>(p + 4);
            u32x4 w; w[0] = lo[0]; w[1] = lo[1]; w[2] = hi[0]; w[3] = hi[1];
            bf[n] = __builtin_bit_cast(bf16x8, w);
        }
#pragma unroll
        for (int i = 0; i < 7; ++i) {
            int t = wv + 4 * i;
            if (t < 25) {
                int row = t * 16 + cl;
                u32x4 ar = *reinterpret_cast<const u32x4*>(&Ad[(size_t)row * KP + kk]);
                bf16x8 af = __builtin_bit_cast(bf16x8, ar);
#pragma unroll
                for (int n = 0; n < 4; ++n)
                    acc[i][n] = __builtin_amdgcn_mfma_f32_16x16x32_bf16(
                        af, bf[n], acc[i][n], 0, 0, 0);
            }
        }
    }

    float bv[4];
#pragma unroll
    for (int n = 0; n < 4; ++n) bv[n] = bias[n * 16 + cl];

    float pmax[4];
#pragma unroll
    for (int n = 0; n < 4; ++n) pmax[n] = -3.4e38f;

#pragma unroll
    for (int i = 0; i < 7; ++i) {
        int t = wv + 4 * i;
        if (t < 25) {
            float y[4][4];
#pragma unroll
            for (int n = 0; n < 4; ++n)
#pragma unroll
                for (int r = 0; r < 4; ++r) y[n][r] = acc[i][n][r] + bv[n];

            float pss[4];
#pragma unroll
            for (int r = 0; r < 4; ++r)
                pss[r] = y[0][r]*y[0][r] + y[1][r]*y[1][r] +
                         y[2][r]*y[2][r] + y[3][r]*y[3][r];
#pragma unroll
            for (int m = 1; m < 16; m <<= 1)
#pragma unroll
                for (int r = 0; r < 4; ++r) pss[r] += __shfl_xor(pss[r], m);

            float rin[4];
#pragma unroll
            for (int r = 0; r < 4; ++r)
                rin[r] = 1.f / fmaxf(sqrtf(pss[r]), 1e-12f);

#pragma unroll
            for (int n = 0; n < 4; ++n)
#pragma unroll
                for (int r = 0; r < 4; ++r) {
                    float z = y[n][r] * rin[r];
                    if (RELU_STATS) z = fmaxf(z, 0.f);
                    y[n][r] = z;
                    int row = t * 16 + g * 4 + r;
                    Zout[((size_t)b * Nn + row) * Hh + n * 16 + cl] = z;
                    if (!RELU_STATS) pmax[n] = fmaxf(pmax[n], z);
                }

            if (RELU_STATS) {
                float s1[4], s2[4];
#pragma unroll
                for (int r = 0; r < 4; ++r) {
                    s1[r] = y[0][r] + y[1][r] + y[2][r] + y[3][r];
                    s2[r] = y[0][r]*y[0][r] + y[1][r]*y[1][r] +
                            y[2][r]*y[2][r] + y[3][r]*y[3][r];
                }
#pragma unroll
                for (int m = 1; m < 16; m <<= 1)
#pragma unroll
                    for (int r = 0; r < 4; ++r) {
                        s1[r] += __shfl_xor(s1[r], m);
                        s2[r] += __shfl_xor(s2[r], m);
                    }
                if (cl == 0) {
#pragma unroll
                    for (int r = 0; r < 4; ++r) {
                        int row = t * 16 + g * 4 + r;
                        atomicAdd(&ssum[row], s1[r]);
                        atomicAdd(&ssq[row],  s2[r]);
                    }
                }
            }
        }
    }

    if constexpr (!RELU_STATS) {
        // fused out3[b,h] = max over all 400 rows (this block owns them all)
        __shared__ float red[16][64];
#pragma unroll
        for (int n = 0; n < 4; ++n) red[wv * 4 + g][n * 16 + cl] = pmax[n];
        __syncthreads();
        if (tid < 64) {
            float m = red[0][tid];
#pragma unroll
            for (int j = 1; j < 16; ++j) m = fmaxf(m, red[j][tid]);
            outmax[b * Hh + tid] = m;
        }
    }
}

__global__ void finalize_stats(const float* __restrict__ ssum,
                               const float* __restrict__ ssq,
                               float* __restrict__ mean, float* __restrict__ inv) {
    int r = threadIdx.x;
    if (r < Nn) {
        float m = ssum[r] * (1.0f / BH_COUNT);
        float v = ssq[r] * (1.0f / BH_COUNT) - m * m;
        mean[r] = m;
        inv[r]  = rsqrtf(v + 1e-5f);
    }
}

// ---------------------------------------------------------------------------
// out[b,h] = max_r (Z[b,r,h]-mean[r])*inv[r]   (layers 1/2; Z f32)
// ---------------------------------------------------------------------------
__global__ __launch_bounds__(256) void maxk(
        const float* __restrict__ Z, const float* __restrict__ mean,
        const float* __restrict__ inv, float* __restrict__ out) {
    __shared__ float red[4][64];
    const int b  = blockIdx.x;
    const int h  = threadIdx.x & 63;
    const int rg = threadIdx.x >> 6;
    float best = -3.4e38f;
    for (int r = rg; r < Nn; r += 4) {
        float v = Z[((size_t)b * Nn + r) * Hh + h];
        v = (v - mean[r]) * inv[r];
        best = fmaxf(best, v);
    }
    red[rg][h] = best;
    __syncthreads();
    if (threadIdx.x < 64) {
        float m = fmaxf(fmaxf(red[0][threadIdx.x], red[1][threadIdx.x]),
                        fmaxf(red[2][threadIdx.x], red[3][threadIdx.x]));
        out[b * Hh + threadIdx.x] = m;
    }
}

// ---------------------------------------------------------------------------
// FC head: h=[out1|out2|out3] (256x192) -> fc1+relu+bn2 -> fc2+relu+bn2 -> fc3
// ---------------------------------------------------------------------------
__global__ __launch_bounds__(1024) void headk(
        const float* __restrict__ out1, const float* __restrict__ out2,
        const float* __restrict__ out3,
        const float* __restrict__ W1f, const float* __restrict__ b1f,
        const float* __restrict__ W2f, const float* __restrict__ b2f,
        const float* __restrict__ W3f, const float* __restrict__ b3f,
        float* __restrict__ ypred) {
    __shared__ float gA[256][64];     // 64 KB activations
    __shared__ float w1s[192 * 64];   // 48 KB
    __shared__ float w2s[64 * 64];    // 16 KB
    __shared__ float mS[64], iS[64];
    const int t = threadIdx.x;
    const int r = t >> 2, q = t & 3;

    for (int i = t; i < 192 * 64; i += 1024) w1s[i] = W1f[i];
    for (int i = t; i < 64 * 64; i += 1024) w2s[i] = W2f[i];
    __syncthreads();

    float acc[16];
#pragma unroll
    for (int j = 0; j < 16; ++j) acc[j] = b1f[q * 16 + j];
    for (int k = 0; k < 192; ++k) {
        float hv = (k < 64) ? out1[r * 64 + k]
                 : (k < 128) ? out2[r * 64 + (k - 64)]
                             : out3[r * 64 + (k - 128)];
#pragma unroll
        for (int j = 0; j < 16; ++j) acc[j] += hv * w1s[k * 64 + q * 16 + j];
    }
#pragma unroll
    for (int j = 0; j < 16; ++j) gA[r][q * 16 + j] = fmaxf(acc[j], 0.f);
    __syncthreads();

    if (t < 64) {
        float s = 0.f, s2 = 0.f;
        for (int rr = 0; rr < 256; ++rr) { float v = gA[rr][t]; s += v; s2 += v * v; }
        float m = s * (1.f / 256.f);
        float var = s2 * (1.f / 256.f) - m * m;
        mS[t] = m;
        iS[t] = rsqrtf(var + 1e-5f);
    }
    __syncthreads();

#pragma unroll
    for (int j = 0; j < 16; ++j) acc[j] = b2f[q * 16 + j];
#pragma unroll
    for (int k = 0; k < 64; ++k) {
        float gn = (gA[r][k] - mS[k]) * iS[k];
#pragma unroll
        for (int j = 0; j < 16; ++j) acc[j] += gn * w2s[k * 64 + q * 16 + j];
    }
    __syncthreads();
#pragma unroll
    for (int j = 0; j < 16; ++j) gA[r][q * 16 + j] = fmaxf(acc[j], 0.f);
    __syncthreads();

    if (t < 64) {
        float s = 0.f, s2 = 0.f;
        for (int rr = 0; rr < 256; ++rr) { float v = gA[rr][t]; s += v; s2 += v * v; }
        float m = s * (1.f / 256.f);
        float var = s2 * (1.f / 256.f) - m * m;
        mS[t] = m;
        iS[t] = rsqrtf(var + 1e-5f);
    }
    __syncthreads();

    if (q < 2) {
        float a = b3f[q];
#pragma unroll
        for (int k = 0; k < 64; ++k) {
            float gn = (gA[r][k] - mS[k]) * iS[k];
            a += gn * W3f[k * 2 + q];
        }
        ypred[r * 2 + q] = a;
    }
}

// ---------------------------------------------------------------------------
extern "C" void kernel_launch(void* const* d_in, const int* in_sizes, int n_in,
                              void* d_out, int out_size, void* d_ws, size_t ws_size,
                              hipStream_t stream) {
    const float* x    = (const float*)d_in[0];
    const int*   arow = (const int*)d_in[1];
    const int*   acol = (const int*)d_in[2];
    const float* aval = (const float*)d_in[3];
    const float* W1 = (const float*)d_in[4];
    const float* b1 = (const float*)d_in[5];
    const float* W2 = (const float*)d_in[6];
    const float* b2 = (const float*)d_in[7];
    const float* W3 = (const float*)d_in[8];
    const float* b3 = (const float*)d_in[9];
    const float* fc1W = (const float*)d_in[10];
    const float* fc1b = (const float*)d_in[11];
    const float* fc2W = (const float*)d_in[12];
    const float* fc2b = (const float*)d_in[13];
    const float* fc3W = (const float*)d_in[14];
    const float* fc3b = (const float*)d_in[15];

    char* w = (char*)d_ws;
    size_t off = 0;
    float* Adf = (float*)(w + off);            off += (size_t)Nn * KP * 4;
    unsigned short* Adbf = (unsigned short*)(w + off); off += (size_t)Nn * KP * 2;
    unsigned short* Ubf  = (unsigned short*)(w + off); off += (size_t)Mrows * Hh * 2;
    float* Z = (float*)(w + off);              off += (size_t)Mrows * Hh * 4;
    float* stats = (float*)(w + off);          off += 1600 * 4;
    float* ssum1 = stats, *ssq1 = stats + 400, *ssum2 = stats + 800, *ssq2 = stats + 1200;
    float* mean1 = (float*)(w + off); off += 1600;
    float* inv1  = (float*)(w + off); off += 1600;
    float* mean2 = (float*)(w + off); off += 1600;
    float* inv2  = (float*)(w + off); off += 1600;
    float* out1  = (float*)(w + off); off += Bb * Hh * 4;
    float* out2  = (float*)(w + off); off += Bb * Hh * 4;
    float* out3  = (float*)(w + off); off += Bb * Hh * 4;

    float* ypred = (float*)d_out;
    float* x3    = (float*)d_out + 512;

    // Densify adjacency -> bf16 [400][416]
    initk<<<(Nn * KP + 1023) / 1024, 1024, 0, stream>>>(Adf, stats);
    scatAk<<<(NNZ + 255) / 256, 256, 0, stream>>>(arow, acol, aval, Adf);
    cvtAk<<<(Nn * KP + 1023) / 1024, 1024, 0, stream>>>(Adf, Adbf);

    // Layer 1: U = x @ W1  (split-precision MFMA, f32-grade)
    xg<FIN, false><<<Mrows / 128, 512, 0, stream>>>(x, W1, Ubf, nullptr, nullptr);
    aggmm<true><<<Bb, 256, 0, stream>>>(Adbf, Ubf, b1, Z, ssum1, ssq1, nullptr);
    finalize_stats<<<1, 512, 0, stream>>>(ssum1, ssq1, mean1, inv1);
    maxk<<<Bb, 256, 0, stream>>>(Z, mean1, inv1, out1);

    // Layer 2 (BN of layer 1 folded into GEMM epilogue)
    xg<Hh, true><<<Mrows / 128, 512, 0, stream>>>(Z, W2, Ubf, mean1, inv1);
    aggmm<true><<<Bb, 256, 0, stream>>>(Adbf, Ubf, b2, Z, ssum2, ssq2, nullptr);
    finalize_stats<<<1, 512, 0, stream>>>(ssum2, ssq2, mean2, inv2);
    maxk<<<Bb, 256, 0, stream>>>(Z, mean2, inv2, out2);

    // Layer 3 (no relu / no BN) -> x3 f32 into d_out, max fused
    xg<Hh, true><<<Mrows / 128, 512, 0, stream>>>(Z, W3, Ubf, mean2, inv2);
    aggmm<false><<<Bb, 256, 0, stream>>>(Adbf, Ubf, b3, x3, nullptr, nullptr, out3);

    // FC head
    headk<<<1, 1024, 0, stream>>>(out1, out2, out3, fc1W, fc1b, fc2W, fc2b,
                                  fc3W, fc3b, ypred);
}